// Round 4
// baseline (207.125 us; speedup 1.0000x reference)
//
#include <hip/hip_runtime.h>
#include <hip/hip_bf16.h>
#include <stdint.h>

typedef unsigned short u16;
typedef __attribute__((ext_vector_type(8))) short short8;
typedef __attribute__((ext_vector_type(4))) float f32x4;
typedef __attribute__((ext_vector_type(4))) u16 u16x4;

#define S_LEN 2048
#define D_DIM 1024
#define NBATCH 4
#define BM 128
#define BN 128
#define BK 32

enum { MODE_SC = 2, MODE_PV = 3 };

__device__ inline u16 f2bf(float f) {
  uint32_t u = __float_as_uint(f);
  uint32_t r = (u + 0x7fffu + ((u >> 16) & 1u)) >> 16;
  return (u16)r;
}

__global__ __launch_bounds__(256) void cast_f32_bf16(
    const float* __restrict__ in, u16* __restrict__ out, int n) {
  int i = (blockIdx.x * blockDim.x + threadIdx.x) * 4;
  int stride = gridDim.x * blockDim.x * 4;
  for (; i < n; i += stride) {
    f32x4 v = *reinterpret_cast<const f32x4*>(in + i);
    u16x4 o;
    o[0] = f2bf(v[0]); o[1] = f2bf(v[1]); o[2] = f2bf(v[2]); o[3] = f2bf(v[3]);
    *reinterpret_cast<u16x4*>(out + i) = o;
  }
}

// ---------------- 256x256 8-phase QKV projection kernel -------------------
// C = A(bf16 [M,K]) * B^T(bf16 [N,K]); N = 3072 = [Wq;Wk;Wv].
// Q,K row-major into segments 0,1; V transposed into segment 2.
template <int H, int V>
__device__ inline void mmq(f32x4 (&acc)[8][4], const short8* af, const short8* bf) {
  __builtin_amdgcn_s_setprio(1);
#pragma unroll
  for (int ii = 0; ii < 4; ++ii)
#pragma unroll
    for (int jj = 0; jj < 2; ++jj)
#pragma unroll
      for (int kk = 0; kk < 2; ++kk)
        acc[H * 4 + ii][V * 2 + jj] = __builtin_amdgcn_mfma_f32_16x16x32_bf16(
            af[ii * 2 + kk], bf[jj * 2 + kk], acc[H * 4 + ii][V * 2 + jj], 0, 0, 0);
  __builtin_amdgcn_s_setprio(0);
}

__global__ __launch_bounds__(512, 2) void gemm_qkv256(
    const u16* __restrict__ A, const u16* __restrict__ B, u16* __restrict__ C, int K) {
  // [buf][quad][128 rows x 64 cols]  (16 KiB per quad slot)
  __shared__ u16 ldsA[2][2][128 * 64];
  __shared__ u16 ldsB[2][2][128 * 64];

  const int nkt = K >> 6;

  // XCD-aware bijective swizzle (nwg = 32*12 = 384, 384 % 8 == 0)
  int lin = blockIdx.y * gridDim.x + blockIdx.x;
  int cpx = (gridDim.x * gridDim.y) >> 3;
  int swzb = (lin & 7) * cpx + (lin >> 3);
  const int br = swzb % gridDim.x;
  const int bc = swzb / gridDim.x;
  const int rowBase = br * 256;
  const int colBase = bc * 256;

  const int tid = threadIdx.x;
  const int lane = tid & 63;
  const int wave = tid >> 6;
  const int wr = wave >> 2;        // 0..1  (row half of 256)
  const int wc = wave & 3;         // 0..3  (col quarter of 256)
  const int l15 = lane & 15;
  const int g = lane >> 4;         // 0..3 (k-slice)
  const int sw = (lane & 7) << 3;  // read-side XOR swizzle (u16 units)

  f32x4 acc[8][4];
#pragma unroll
  for (int i = 0; i < 8; i++)
#pragma unroll
    for (int j = 0; j < 4; j++) acc[i][j] = f32x4{0.f, 0.f, 0.f, 0.f};

  // staging thread mapping: m = q*64 + (tid>>3) is the within-quad row index,
  // source column slot pre-permuted so data lands swizzled in linear LDS.
  const int mrow = tid >> 3;                  // 0..63
  const int slot = (tid & 7) ^ (mrow & 7);    // inverse-swizzled 16B slot

  auto stA = [&](int buf, int h, int kt) {
    // A-quad h holds global rows {w*128 + h*64 + rr : w in 0..1, rr in 0..63},
    // LDS order m = w*64 + rr.
#pragma unroll
    for (int q = 0; q < 2; ++q) {
      int grow = rowBase + q * 128 + h * 64 + mrow;
      const u16* src = A + (long)grow * K + kt * 64 + slot * 8;
      __builtin_amdgcn_global_load_lds(
          (const __attribute__((address_space(1))) void*)src,
          (__attribute__((address_space(3))) void*)(&ldsA[buf][h][q * 4096 + tid * 8]),
          16, 0, 0);
    }
  };
  auto stB = [&](int buf, int v, int kt) {
    // B-quad v holds cols c = wcq*64 + v*32 + rr (wcq 0..3, rr 0..31), m = wcq*32+rr.
#pragma unroll
    for (int q = 0; q < 2; ++q) {
      int m = q * 64 + mrow;
      int gcol = colBase + (m >> 5) * 64 + v * 32 + (m & 31);
      const u16* src = B + (long)gcol * K + kt * 64 + slot * 8;
      __builtin_amdgcn_global_load_lds(
          (const __attribute__((address_space(1))) void*)src,
          (__attribute__((address_space(3))) void*)(&ldsB[buf][v][q * 4096 + tid * 8]),
          16, 0, 0);
    }
  };

  short8 aF[8], bL[4], bH[4];

  auto rdA = [&](short8* d, int buf, int h) {
    const u16* base = &ldsA[buf][h][wr * 4096];
#pragma unroll
    for (int ii = 0; ii < 4; ++ii)
#pragma unroll
      for (int kk = 0; kk < 2; ++kk) {
        int idx = (((ii * 16 + l15) * 64) + kk * 32 + g * 8) ^ sw;
        d[ii * 2 + kk] = *reinterpret_cast<const short8*>(base + idx);
      }
  };
  auto rdB = [&](short8* d, int buf, int v) {
    const u16* base = &ldsB[buf][v][wc * 2048];
#pragma unroll
    for (int jj = 0; jj < 2; ++jj)
#pragma unroll
      for (int kk = 0; kk < 2; ++kk) {
        int idx = (((jj * 16 + l15) * 64) + kk * 32 + g * 8) ^ sw;
        d[jj * 2 + kk] = *reinterpret_cast<const short8*>(base + idx);
      }
  };

  // prologue: K-tiles 0 and 1
  stA(0, 0, 0); stA(0, 1, 0); stB(0, 0, 0); stB(0, 1, 0);
  if (nkt > 1) {
    stA(1, 0, 1); stA(1, 1, 1); stB(1, 0, 1); stB(1, 1, 1);
    asm volatile("s_waitcnt vmcnt(8)" ::: "memory");
  } else {
    asm volatile("s_waitcnt vmcnt(0)" ::: "memory");
  }
  __builtin_amdgcn_s_barrier();

  auto ktile = [&](int buf, int t) {
    const bool pf = (t + 2 < nkt);
    // phase 1: Q00
    rdA(aF, buf, 0);
    rdB(bL, buf, 0);
    __builtin_amdgcn_s_barrier();
    mmq<0, 0>(acc, aF, bL);
    __builtin_amdgcn_s_barrier();
    // phase 2: Q01  (A-quad0 & B-quad0 slots now free)
    if (pf) { stA(buf, 0, t + 2); stB(buf, 0, t + 2); }
    rdB(bH, buf, 1);
    __builtin_amdgcn_s_barrier();
    mmq<0, 1>(acc, aF, bH);
    __builtin_amdgcn_s_barrier();
    // phase 3: Q11  (B-quad1 slot free after phase 2)
    if (pf) stB(buf, 1, t + 2);
    rdA(aF, buf, 1);
    __builtin_amdgcn_s_barrier();
    mmq<1, 1>(acc, aF, bH);
    __builtin_amdgcn_s_barrier();
    // phase 4: Q10  (regs only; A-quad1 slot free after phase 3)
    if (pf) stA(buf, 1, t + 2);
    mmq<1, 0>(acc, aF, bL);
    if (pf) asm volatile("s_waitcnt vmcnt(8)" ::: "memory");
    else    asm volatile("s_waitcnt vmcnt(0)" ::: "memory");
    __builtin_amdgcn_s_barrier();
  };

  for (int t = 0; t < nkt; t += 2) {
    ktile(0, t);
    if (t + 1 < nkt) ktile(1, t + 1);
  }

  // epilogue: route Q/K row-major, V transposed
  const int lr = g * 4;
  const long seg = (long)NBATCH * S_LEN * D_DIM;
  const int segi = colBase >> 10;   // 256-tiles never straddle 1024 boundaries
  const int hb = colBase & 1023;
  if (segi < 2) {
    u16* dst = C + (long)segi * seg;
#pragma unroll
    for (int i = 0; i < 8; i++) {
      int r0 = rowBase + wr * 128 + i * 16 + lr;
#pragma unroll
      for (int j = 0; j < 4; j++) {
        int c0 = hb + wc * 64 + j * 16 + l15;
#pragma unroll
        for (int q = 0; q < 4; q++) dst[(long)(r0 + q) * D_DIM + c0] = f2bf(acc[i][j][q]);
      }
    }
  } else {
    u16* dst = C + 2 * seg;  // Vt [NBATCH][D_DIM][S_LEN]
#pragma unroll
    for (int i = 0; i < 8; i++) {
      int m0 = rowBase + wr * 128 + i * 16 + lr;
      int b = m0 >> 11, s0 = m0 & (S_LEN - 1);
#pragma unroll
      for (int j = 0; j < 4; j++) {
        int h = hb + wc * 64 + j * 16 + l15;
        u16x4 o;
        o[0] = f2bf(acc[i][j][0]); o[1] = f2bf(acc[i][j][1]);
        o[2] = f2bf(acc[i][j][2]); o[3] = f2bf(acc[i][j][3]);
        *reinterpret_cast<u16x4*>(dst + ((long)b * D_DIM + h) * S_LEN + s0) = o;
      }
    }
  }
}

// ---------------- 128x128 kernel for SC (triangular) and PV ---------------
template <int MODE>
__global__ __launch_bounds__(256, 2) void gemm_bt(
    const u16* __restrict__ A, const u16* __restrict__ B, float* __restrict__ C,
    int K, long strideAb, long strideBb, long strideCb, int ldc) {
  __shared__ u16 As[2][BM * BK];
  __shared__ u16 Bs[2][BN * BK];

  const int bz = blockIdx.z;
  const u16* Ab = A + (long)bz * strideAb;
  const u16* Bb = B + (long)bz * strideBb;

  int br, bc;
  if (MODE == MODE_SC) {
    int t = blockIdx.x;
    int r = (int)((sqrtf(8.0f * (float)t + 1.0f) - 1.0f) * 0.5f);
    while ((r + 1) * (r + 2) / 2 <= t) ++r;
    while (r * (r + 1) / 2 > t) --r;
    br = r;
    bc = t - r * (r + 1) / 2;
  } else {
    // heavy/light interleave for triangular PV load balance
    int xr = blockIdx.x;
    int nt = gridDim.x;
    br = (xr & 1) ? (xr >> 1) : (nt - 1 - (xr >> 1));
    bc = blockIdx.y;
  }

  const int rowBase = br * BM;
  const int colBase = bc * BN;
  int nkt = (MODE == MODE_PV) ? (br + 1) * (BM / BK) : (K / BK);

  const int tid = threadIdx.x;
  const int lane = tid & 63;
  const int wave = tid >> 6;
  const int wr = wave >> 1, wc = wave & 1;

  f32x4 acc[4][4];
#pragma unroll
  for (int i = 0; i < 4; i++)
#pragma unroll
    for (int j = 0; j < 4; j++) acc[i][j] = f32x4{0.f, 0.f, 0.f, 0.f};

  const int srow = tid >> 2;
  const int skc = (tid & 3) * 8;

  auto stage = [&](int buf, int kt) {
    const u16* ga = Ab + (long)(rowBase + srow) * K + kt * BK + skc;
    const u16* gb = Bb + (long)(colBase + srow) * K + kt * BK + skc;
    __builtin_amdgcn_global_load_lds(
        (const __attribute__((address_space(1))) void*)ga,
        (__attribute__((address_space(3))) void*)(&As[buf][tid * 8]), 16, 0, 0);
    __builtin_amdgcn_global_load_lds(
        (const __attribute__((address_space(1))) void*)(ga + (long)64 * K),
        (__attribute__((address_space(3))) void*)(&As[buf][64 * BK + tid * 8]), 16, 0, 0);
    __builtin_amdgcn_global_load_lds(
        (const __attribute__((address_space(1))) void*)gb,
        (__attribute__((address_space(3))) void*)(&Bs[buf][tid * 8]), 16, 0, 0);
    __builtin_amdgcn_global_load_lds(
        (const __attribute__((address_space(1))) void*)(gb + (long)64 * K),
        (__attribute__((address_space(3))) void*)(&Bs[buf][64 * BK + tid * 8]), 16, 0, 0);
  };

  stage(0, 0);
  int cur = 0;
  for (int kt = 0; kt < nkt; ++kt) {
    if (kt + 1 < nkt) stage(cur ^ 1, kt + 1);
    __syncthreads();
    short8 af[4], bf[4];
#pragma unroll
    for (int i = 0; i < 4; i++)
      af[i] = *reinterpret_cast<const short8*>(
          &As[cur][(wr * 64 + i * 16 + (lane & 15)) * BK + (lane >> 4) * 8]);
#pragma unroll
    for (int j = 0; j < 4; j++)
      bf[j] = *reinterpret_cast<const short8*>(
          &Bs[cur][(wc * 64 + j * 16 + (lane & 15)) * BK + (lane >> 4) * 8]);
#pragma unroll
    for (int i = 0; i < 4; i++)
#pragma unroll
      for (int j = 0; j < 4; j++)
        acc[i][j] = __builtin_amdgcn_mfma_f32_16x16x32_bf16(af[i], bf[j], acc[i][j], 0, 0, 0);
    __syncthreads();
    cur ^= 1;
  }

  const int lr = (lane >> 4) * 4;
  const int lc = lane & 15;
  float* Cb = C + (long)bz * strideCb;
#pragma unroll
  for (int i = 0; i < 4; i++) {
    int r0 = rowBase + wr * 64 + i * 16 + lr;
#pragma unroll
    for (int j = 0; j < 4; j++) {
      int c0 = colBase + wc * 64 + j * 16 + lc;
#pragma unroll
      for (int q = 0; q < 4; q++) Cb[(long)(r0 + q) * ldc + c0] = acc[i][j][q];
    }
  }
}

// one block per row: masked scaled softmax over cols [0, i], zero-fill to 128-boundary.
__global__ __launch_bounds__(256) void softmax_causal(
    const float* __restrict__ scores, u16* __restrict__ P, long strideSb, long stridePb) {
  const int b = blockIdx.z;
  const int i = blockIdx.x;
  const float* srow = scores + (long)b * strideSb + (long)i * S_LEN;
  u16* prow = P + (long)b * stridePb + (long)i * S_LEN;
  const int W = ((i >> 7) + 1) << 7;
  const int tid = threadIdx.x;
  const int lane = tid & 63;
  const int wave = tid >> 6;

  f32x4 v[2];
  int nc = 0;
  float lmax = -1e30f;
  for (int j = tid * 4; j < W; j += 1024) {
    f32x4 x = *reinterpret_cast<const f32x4*>(srow + j);
#pragma unroll
    for (int q = 0; q < 4; q++) {
      x[q] = (j + q <= i) ? x[q] * 0.03125f : -1e30f;
      lmax = fmaxf(lmax, x[q]);
    }
    v[nc++] = x;
  }
#pragma unroll
  for (int off = 32; off; off >>= 1) lmax = fmaxf(lmax, __shfl_xor(lmax, off));
  __shared__ float redm[4], reds[4];
  if (lane == 0) redm[wave] = lmax;
  __syncthreads();
  const float m = fmaxf(fmaxf(redm[0], redm[1]), fmaxf(redm[2], redm[3]));

  float lsum = 0.f;
  int c = 0;
  for (int j = tid * 4; j < W; j += 1024, ++c) {
#pragma unroll
    for (int q = 0; q < 4; q++) {
      float p = __expf(v[c][q] - m);
      v[c][q] = p;
      lsum += p;
    }
  }
#pragma unroll
  for (int off = 32; off; off >>= 1) lsum += __shfl_xor(lsum, off);
  if (lane == 0) reds[wave] = lsum;
  __syncthreads();
  const float inv = 1.f / (reds[0] + reds[1] + reds[2] + reds[3]);

  c = 0;
  for (int j = tid * 4; j < W; j += 1024, ++c) {
    u16x4 o;
#pragma unroll
    for (int q = 0; q < 4; q++) o[q] = f2bf(v[c][q] * inv);
    *reinterpret_cast<u16x4*>(prow + j) = o;
  }
}

extern "C" void kernel_launch(void* const* d_in, const int* in_sizes, int n_in,
                              void* d_out, int out_size, void* d_ws, size_t ws_size,
                              hipStream_t stream) {
  const float* x = (const float*)d_in[0];
  const float* Wq = (const float*)d_in[1];
  const float* Wk = (const float*)d_in[2];
  const float* Wv = (const float*)d_in[3];
  float* out = (float*)d_out;

  const size_t SD = (size_t)S_LEN * D_DIM;
  const size_t SS = (size_t)S_LEN * S_LEN;
  const size_t DD = (size_t)D_DIM * D_DIM;

  size_t off = 0;
  char* ws = (char*)d_ws;
  auto alloc = [&](size_t bytes) -> char* {
    char* p = ws + off;
    off += (bytes + 255) & ~(size_t)255;
    return p;
  };
  u16* xb = (u16*)alloc(NBATCH * SD * 2);
  u16* Wqkvb = (u16*)alloc(3 * DD * 2);           // [Wq;Wk;Wv] rows, [3072,1024]
  u16* QKVt = (u16*)alloc(3 * NBATCH * SD * 2);   // Qb | Kb | Vt contiguous
  u16* Qb = QKVt;
  u16* Kb = QKVt + NBATCH * SD;
  u16* Vt = QKVt + 2 * NBATCH * SD;
  size_t need_full = off + ((NBATCH * SS * 4 + 255) & ~(size_t)255) +
                     ((NBATCH * SS * 2 + 255) & ~(size_t)255);
  const int nbpar = (ws_size >= need_full) ? NBATCH : 1;
  float* scores = (float*)alloc((size_t)nbpar * SS * 4);
  u16* P = (u16*)alloc((size_t)nbpar * SS * 2);

  cast_f32_bf16<<<2048, 256, 0, stream>>>(x, xb, (int)(NBATCH * SD));
  cast_f32_bf16<<<512, 256, 0, stream>>>(Wq, Wqkvb, (int)DD);
  cast_f32_bf16<<<512, 256, 0, stream>>>(Wk, Wqkvb + DD, (int)DD);
  cast_f32_bf16<<<512, 256, 0, stream>>>(Wv, Wqkvb + 2 * DD, (int)DD);

  // fused QKV projection: M = 8192, N = 3072, K = 1024, 256^2 8-phase
  dim3 g256((NBATCH * S_LEN) / 256, (3 * D_DIM) / 256, 1);
  gemm_qkv256<<<g256, 512, 0, stream>>>(xb, Wqkvb, QKVt, D_DIM);

  const int ntri = (S_LEN / BM) * (S_LEN / BM + 1) / 2;  // 136
  if (nbpar == NBATCH) {
    gemm_bt<MODE_SC><<<dim3(ntri, 1, NBATCH), 256, 0, stream>>>(
        Qb, Kb, scores, D_DIM, (long)SD, (long)SD, (long)SS, S_LEN);
    softmax_causal<<<dim3(S_LEN, 1, NBATCH), 256, 0, stream>>>(scores, P, (long)SS, (long)SS);
    gemm_bt<MODE_PV><<<dim3(S_LEN / BM, D_DIM / BN, NBATCH), 256, 0, stream>>>(
        P, Vt, out, S_LEN, (long)SS, (long)SD, (long)SD, D_DIM);
  } else {
    for (int b = 0; b < NBATCH; ++b) {
      gemm_bt<MODE_SC><<<dim3(ntri, 1, 1), 256, 0, stream>>>(
          Qb + b * SD, Kb + b * SD, scores, D_DIM, 0, 0, 0, S_LEN);
      softmax_causal<<<dim3(S_LEN, 1, 1), 256, 0, stream>>>(scores, P, 0, 0);
      gemm_bt<MODE_PV><<<dim3(S_LEN / BM, D_DIM / BN, 1), 256, 0, stream>>>(
          P, Vt + b * SD, out + b * SD, S_LEN, 0, 0, 0, D_DIM);
    }
  }
}

// Round 5
// 186.002 us; speedup vs baseline: 1.1136x; 1.1136x over previous
//
#include <hip/hip_runtime.h>
#include <hip/hip_bf16.h>
#include <stdint.h>

typedef unsigned short u16;
typedef __attribute__((ext_vector_type(8))) short short8;
typedef __attribute__((ext_vector_type(4))) float f32x4;
typedef __attribute__((ext_vector_type(4))) u16 u16x4;

#define S_LEN 2048
#define D_DIM 1024
#define NBATCH 4
#define BM 128
#define BN 128
#define BK 32

enum { MODE_QKV = 0, MODE_SC = 2, MODE_PV = 3 };

__device__ inline u16 f2bf(float f) {
  uint32_t u = __float_as_uint(f);
  uint32_t r = (u + 0x7fffu + ((u >> 16) & 1u)) >> 16;
  return (u16)r;
}

__global__ __launch_bounds__(256) void cast_f32_bf16(
    const float* __restrict__ in, u16* __restrict__ out, int n) {
  int i = (blockIdx.x * blockDim.x + threadIdx.x) * 4;
  int stride = gridDim.x * blockDim.x * 4;
  for (; i < n; i += stride) {
    f32x4 v = *reinterpret_cast<const f32x4*>(in + i);
    u16x4 o;
    o[0] = f2bf(v[0]); o[1] = f2bf(v[1]); o[2] = f2bf(v[2]); o[3] = f2bf(v[3]);
    *reinterpret_cast<u16x4*>(out + i) = o;
  }
}

// C = A (bf16 [M,K]) * B^T (bf16 [N,K]) ; lda = ldb = K.
// MODE_QKV: B = [Wq;Wk;Wv] (N=3072); Q,K row-major segments, V transposed segment.
// MODE_SC : triangular grid; epilogue = mask + exp(s/32 - 8) -> bf16 P' + partial row sums.
// MODE_PV : K truncated at diagonal; epilogue scales by 1/l (aux).
template <int MODE>
__global__ __launch_bounds__(256, 2) void gemm_bt(
    const u16* __restrict__ A, const u16* __restrict__ B, void* __restrict__ C,
    int K, long strideAb, long strideBb, long strideCb, int ldc,
    float* __restrict__ aux) {
  __shared__ u16 As[2][BM * BK];
  __shared__ u16 Bs[2][BN * BK];

  const int bz = blockIdx.z;
  const u16* Ab = A + (long)bz * strideAb;
  const u16* Bb = B + (long)bz * strideBb;

  int br, bc;
  if (MODE == MODE_SC) {
    int t = blockIdx.x;
    int r = (int)((sqrtf(8.0f * (float)t + 1.0f) - 1.0f) * 0.5f);
    while ((r + 1) * (r + 2) / 2 <= t) ++r;
    while (r * (r + 1) / 2 > t) --r;
    br = r;
    bc = t - r * (r + 1) / 2;
  } else if (MODE == MODE_PV) {
    // heavy/light interleave for triangular load balance
    int xr = blockIdx.x;
    int nt = gridDim.x;
    br = (xr & 1) ? (xr >> 1) : (nt - 1 - (xr >> 1));
    bc = blockIdx.y;
  } else {
    // MODE_QKV: XCD-aware swizzle over the flat 64x24 grid (1536 % 8 == 0).
    int lin = blockIdx.y * gridDim.x + blockIdx.x;
    int nwg = gridDim.x * gridDim.y;
    int cpx = nwg >> 3;
    int swz = (lin & 7) * cpx + (lin >> 3);
    br = swz % gridDim.x;
    bc = swz / gridDim.x;
  }

  const int rowBase = br * BM;
  const int colBase = bc * BN;
  int nkt = (MODE == MODE_PV) ? (br + 1) * (BM / BK) : (K / BK);

  const int tid = threadIdx.x;
  const int lane = tid & 63;
  const int wave = tid >> 6;
  const int wr = wave >> 1, wc = wave & 1;

  f32x4 acc[4][4];
#pragma unroll
  for (int i = 0; i < 4; i++)
#pragma unroll
    for (int j = 0; j < 4; j++) acc[i][j] = f32x4{0.f, 0.f, 0.f, 0.f};

  const int srow = tid >> 2;
  const int skc = (tid & 3) * 8;

  auto stage = [&](int buf, int kt) {
    const u16* ga = Ab + (long)(rowBase + srow) * K + kt * BK + skc;
    const u16* gb = Bb + (long)(colBase + srow) * K + kt * BK + skc;
    __builtin_amdgcn_global_load_lds(
        (const __attribute__((address_space(1))) void*)ga,
        (__attribute__((address_space(3))) void*)(&As[buf][tid * 8]), 16, 0, 0);
    __builtin_amdgcn_global_load_lds(
        (const __attribute__((address_space(1))) void*)(ga + (long)64 * K),
        (__attribute__((address_space(3))) void*)(&As[buf][64 * BK + tid * 8]), 16, 0, 0);
    __builtin_amdgcn_global_load_lds(
        (const __attribute__((address_space(1))) void*)gb,
        (__attribute__((address_space(3))) void*)(&Bs[buf][tid * 8]), 16, 0, 0);
    __builtin_amdgcn_global_load_lds(
        (const __attribute__((address_space(1))) void*)(gb + (long)64 * K),
        (__attribute__((address_space(3))) void*)(&Bs[buf][64 * BK + tid * 8]), 16, 0, 0);
  };

  stage(0, 0);
  int cur = 0;
  for (int kt = 0; kt < nkt; ++kt) {
    if (kt + 1 < nkt) stage(cur ^ 1, kt + 1);
    __syncthreads();
    short8 af[4], bf[4];
#pragma unroll
    for (int i = 0; i < 4; i++)
      af[i] = *reinterpret_cast<const short8*>(
          &As[cur][(wr * 64 + i * 16 + (lane & 15)) * BK + (lane >> 4) * 8]);
#pragma unroll
    for (int j = 0; j < 4; j++)
      bf[j] = *reinterpret_cast<const short8*>(
          &Bs[cur][(wc * 64 + j * 16 + (lane & 15)) * BK + (lane >> 4) * 8]);
#pragma unroll
    for (int i = 0; i < 4; i++)
#pragma unroll
      for (int j = 0; j < 4; j++)
        acc[i][j] = __builtin_amdgcn_mfma_f32_16x16x32_bf16(af[i], bf[j], acc[i][j], 0, 0, 0);
    __syncthreads();
    cur ^= 1;
  }

  const int lr = (lane >> 4) * 4;
  const int lc = lane & 15;

  if (MODE == MODE_QKV) {
    u16* Cb = (u16*)C;  // Qb base; Kb at +seg; Vt at +2*seg
    const long seg = (long)NBATCH * S_LEN * D_DIM;
    const int segi = colBase >> 10;
    const int hb = colBase & 1023;
    if (segi < 2) {
      u16* dst = Cb + (long)segi * seg;
#pragma unroll
      for (int i = 0; i < 4; i++) {
        int r0 = rowBase + wr * 64 + i * 16 + lr;
#pragma unroll
        for (int j = 0; j < 4; j++) {
          int c0 = hb + wc * 64 + j * 16 + lc;
#pragma unroll
          for (int q = 0; q < 4; q++) dst[(long)(r0 + q) * D_DIM + c0] = f2bf(acc[i][j][q]);
        }
      }
    } else {
      u16* dst = Cb + 2 * seg;  // Vt [NBATCH][D_DIM][S_LEN]
#pragma unroll
      for (int i = 0; i < 4; i++) {
        int m0 = rowBase + wr * 64 + i * 16 + lr;
        int b = m0 >> 11, s0 = m0 & (S_LEN - 1);
#pragma unroll
        for (int j = 0; j < 4; j++) {
          int h = hb + wc * 64 + j * 16 + lc;
          u16x4 o;
          o[0] = f2bf(acc[i][j][0]); o[1] = f2bf(acc[i][j][1]);
          o[2] = f2bf(acc[i][j][2]); o[3] = f2bf(acc[i][j][3]);
          *reinterpret_cast<u16x4*>(dst + ((long)b * D_DIM + h) * S_LEN + s0) = o;
        }
      }
    }
  } else if (MODE == MODE_SC) {
    // P' = exp(s/32 - 8), causally masked; partial row sums -> aux[b][row][32]
    u16* Cb = (u16*)C + (long)bz * strideCb;
    float* lp = aux + (long)bz * S_LEN * 32;
#pragma unroll
    for (int i = 0; i < 4; i++) {
      int r0 = rowBase + wr * 64 + i * 16 + lr;
#pragma unroll
      for (int q = 0; q < 4; q++) {
        int r = r0 + q;
        float rs = 0.f;
#pragma unroll
        for (int j = 0; j < 4; j++) {
          int c0 = colBase + wc * 64 + j * 16 + lc;
          float p = (c0 <= r) ? __expf(acc[i][j][q] * 0.03125f - 8.f) : 0.f;
          rs += p;
          Cb[(long)r * ldc + c0] = f2bf(p);
        }
#pragma unroll
        for (int off = 1; off < 16; off <<= 1) rs += __shfl_xor(rs, off);
        if ((lane & 15) == 0) lp[r * 32 + bc * 2 + wc] = rs;
      }
    }
  } else {
    // MODE_PV: scale rows by 1/l
    float* Cb = (float*)C + (long)bz * strideCb;
    const float* il = aux + (long)bz * S_LEN;
#pragma unroll
    for (int i = 0; i < 4; i++) {
      int r0 = rowBase + wr * 64 + i * 16 + lr;
#pragma unroll
      for (int j = 0; j < 4; j++) {
        int c0 = colBase + wc * 64 + j * 16 + lc;
#pragma unroll
        for (int q = 0; q < 4; q++)
          Cb[(long)(r0 + q) * ldc + c0] = acc[i][j][q] * il[r0 + q];
      }
    }
  }
}

// inv_l[row] = 1 / sum(l_part[row][0:32])
__global__ __launch_bounds__(256) void row_inv(
    const float* __restrict__ lp, float* __restrict__ il, int nrows) {
  int r = blockIdx.x * blockDim.x + threadIdx.x;
  if (r < nrows) {
    const float* p = lp + (long)r * 32;
    float s = 0.f;
#pragma unroll
    for (int k = 0; k < 32; k += 4) {
      f32x4 v = *reinterpret_cast<const f32x4*>(p + k);
      s += v[0] + v[1] + v[2] + v[3];
    }
    il[r] = 1.f / s;
  }
}

extern "C" void kernel_launch(void* const* d_in, const int* in_sizes, int n_in,
                              void* d_out, int out_size, void* d_ws, size_t ws_size,
                              hipStream_t stream) {
  const float* x = (const float*)d_in[0];
  const float* Wq = (const float*)d_in[1];
  const float* Wk = (const float*)d_in[2];
  const float* Wv = (const float*)d_in[3];
  float* out = (float*)d_out;

  const size_t SD = (size_t)S_LEN * D_DIM;
  const size_t SS = (size_t)S_LEN * S_LEN;
  const size_t DD = (size_t)D_DIM * D_DIM;

  size_t off = 0;
  char* ws = (char*)d_ws;
  auto alloc = [&](size_t bytes) -> char* {
    char* p = ws + off;
    off += (bytes + 255) & ~(size_t)255;
    return p;
  };
  u16* xb = (u16*)alloc(NBATCH * SD * 2);
  u16* Wqkvb = (u16*)alloc(3 * DD * 2);           // [Wq;Wk;Wv] rows, [3072,1024]
  u16* QKVt = (u16*)alloc(3 * NBATCH * SD * 2);   // Qb | Kb | Vt contiguous
  u16* Qb = QKVt;
  u16* Kb = QKVt + NBATCH * SD;
  u16* Vt = QKVt + 2 * NBATCH * SD;
  size_t base_off = off;
  size_t need_full = base_off + ((NBATCH * SS * 2 + 255) & ~(size_t)255) +
                     ((NBATCH * (size_t)S_LEN * 32 * 4 + 255) & ~(size_t)255) +
                     ((NBATCH * (size_t)S_LEN * 4 + 255) & ~(size_t)255);
  const int nbpar = (ws_size >= need_full) ? NBATCH : 1;
  u16* P = (u16*)alloc((size_t)nbpar * SS * 2);
  float* l_part = (float*)alloc((size_t)nbpar * S_LEN * 32 * 4);
  float* inv_l = (float*)alloc((size_t)nbpar * S_LEN * 4);

  cast_f32_bf16<<<2048, 256, 0, stream>>>(x, xb, (int)(NBATCH * SD));
  cast_f32_bf16<<<512, 256, 0, stream>>>(Wq, Wqkvb, (int)DD);
  cast_f32_bf16<<<512, 256, 0, stream>>>(Wk, Wqkvb + DD, (int)DD);
  cast_f32_bf16<<<512, 256, 0, stream>>>(Wv, Wqkvb + 2 * DD, (int)DD);

  // fused QKV projection: M = 8192, N = 3072, K = 1024 (2-phase 128^2, 6 blk/CU)
  dim3 gp((NBATCH * S_LEN) / BM, 3 * D_DIM / BN, 1);
  gemm_bt<MODE_QKV><<<gp, 256, 0, stream>>>(xb, Wqkvb, QKVt, D_DIM, 0, 0, 0, D_DIM, nullptr);

  const int ntri = (S_LEN / BM) * (S_LEN / BM + 1) / 2;  // 136
  if (nbpar == NBATCH) {
    hipMemsetAsync(l_part, 0, (size_t)NBATCH * S_LEN * 32 * 4, stream);
    gemm_bt<MODE_SC><<<dim3(ntri, 1, NBATCH), 256, 0, stream>>>(
        Qb, Kb, P, D_DIM, (long)SD, (long)SD, (long)SS, S_LEN, l_part);
    row_inv<<<dim3(NBATCH * S_LEN / 256), 256, 0, stream>>>(l_part, inv_l, NBATCH * S_LEN);
    gemm_bt<MODE_PV><<<dim3(S_LEN / BM, D_DIM / BN, NBATCH), 256, 0, stream>>>(
        P, Vt, out, S_LEN, (long)SS, (long)SD, (long)SD, D_DIM, inv_l);
  } else {
    for (int b = 0; b < NBATCH; ++b) {
      hipMemsetAsync(l_part, 0, (size_t)S_LEN * 32 * 4, stream);
      gemm_bt<MODE_SC><<<dim3(ntri, 1, 1), 256, 0, stream>>>(
          Qb + b * SD, Kb + b * SD, P, D_DIM, 0, 0, 0, S_LEN, l_part);
      row_inv<<<dim3(S_LEN / 256), 256, 0, stream>>>(l_part, inv_l, S_LEN);
      gemm_bt<MODE_PV><<<dim3(S_LEN / BM, D_DIM / BN, 1), 256, 0, stream>>>(
          P, Vt + b * SD, out + b * SD, S_LEN, 0, 0, 0, D_DIM, inv_l);
    }
  }
}